// Round 7
// baseline (98.422 us; speedup 1.0000x reference)
//
#include <hip/hip_runtime.h>
#include <hip/hip_bf16.h>

#define OUT_N 8192
#define IN_K  8192
#define M_ROWS 64

typedef __attribute__((ext_vector_type(8))) short  bf16x8;
typedef __attribute__((ext_vector_type(4))) float  f32x4;
typedef __attribute__((ext_vector_type(4))) int    int4v;

__device__ const float NF4_TAB[16] = {
  -1.0f, -0.6961928009986877f, -0.5250730514526367f, -0.39491748809814453f,
  -0.28444138169288635f, -0.18477343022823334f, -0.09105003625154495f, 0.0f,
  0.07958029955625534f, 0.16093020141124725f, 0.24611230850219726f,
  0.33791524171829224f, 0.44070982933044434f, 0.5626170039176941f,
  0.7229568362236023f, 1.0f };

static __device__ __forceinline__ unsigned short f2bf(float f) {
  union { __hip_bfloat16 h; unsigned short s; } u;
  u.h = __float2bfloat16(f);
  return u.s;
}

static __device__ __forceinline__ void gload_lds16(const void* g, void* s) {
  __builtin_amdgcn_global_load_lds((const __attribute__((address_space(1))) void*)g,
                                   (__attribute__((address_space(3))) void*)s,
                                   16, 0, 0);
}

// Repack x (fp32 [64][8192]) -> bf16 MFMA A-fragment order.
// xf[((ks*4 + mt)*64 + lane)*8 + j] = bf16(x[mt*16+(lane&15)][ks*32+(lane>>4)*8+j])
__global__ __launch_bounds__(256) void qlin_prep(const float* __restrict__ x,
                                                 unsigned short* __restrict__ xf) {
  int t = blockIdx.x * 256 + threadIdx.x;          // (ks, mt, lane)
  int lane = t & 63, mt = (t >> 6) & 3, ks = t >> 8;
  int ri = lane & 15, kbb = lane >> 4;
  const float* src = x + (size_t)(mt * 16 + ri) * IN_K + ks * 32 + kbb * 8;
  f32x4 a = *(const f32x4*)src;
  f32x4 c = *(const f32x4*)(src + 4);
  bf16x8 o;
  o[0] = (short)f2bf(a[0]); o[1] = (short)f2bf(a[1]);
  o[2] = (short)f2bf(a[2]); o[3] = (short)f2bf(a[3]);
  o[4] = (short)f2bf(c[0]); o[5] = (short)f2bf(c[1]);
  o[6] = (short)f2bf(c[2]); o[7] = (short)f2bf(c[3]);
  ((bf16x8*)xf)[t] = o;
}

static __device__ __forceinline__ bf16x8 deq(const unsigned int* lut, int4v cur) {
  int4v bw;
  bw[0] = (int)lut[cur[0] & 255];
  bw[1] = (int)lut[cur[1] & 255];
  bw[2] = (int)lut[cur[2] & 255];
  bw[3] = (int)lut[cur[3] & 255];
  union { int4v i; bf16x8 h; } c; c.i = bw;
  return c.h;
}

// wave w stages k-step (4*(PH) + w) of the chunk into LDS buffer B.
// xf k-step block is 4096B, laid out exactly as lane-linear 256x16B.
#define STAGE(B, PH) {                                                        \
    const char* _s = xfb + (size_t)(PH) * 16384 + w * 4096 + l * 16;          \
    char* _d = astage + (B) * 16384 + w * 4096;                               \
    gload_lds16(_s,          _d);                                             \
    gload_lds16(_s + 1024,   _d + 1024);                                      \
    gload_lds16(_s + 2048,   _d + 2048);                                      \
    gload_lds16(_s + 3072,   _d + 3072); }

// one k-step: A-fragments from LDS, dequant pk, 4 MFMA, reload pk (+4 ahead).
// EVEN opens a 64k group (C=0), ODD closes it (fold absmax into mn).
#define CSTEP_EVEN(S, PKV) {                                                  \
    int _nk = KS + (S) + 4; if (_nk > NITm1) _nk = NITm1;                     \
    int4v _npk = *(const int4v*)(pbase + (size_t)_nk * 64);                   \
    const char* _ab = abase + (S) * 4096;                                     \
    bf16x8 A0 = *(const bf16x8*)(_ab);                                        \
    bf16x8 A1 = *(const bf16x8*)(_ab + 1024);                                 \
    bf16x8 A2 = *(const bf16x8*)(_ab + 2048);                                 \
    bf16x8 A3 = *(const bf16x8*)(_ab + 3072);                                 \
    bf16x8 b = deq(lut, PKV);                                                 \
    sb0 = __builtin_amdgcn_mfma_f32_16x16x32_bf16(A0, b, zro, 0, 0, 0);       \
    sb1 = __builtin_amdgcn_mfma_f32_16x16x32_bf16(A1, b, zro, 0, 0, 0);       \
    sb2 = __builtin_amdgcn_mfma_f32_16x16x32_bf16(A2, b, zro, 0, 0, 0);       \
    sb3 = __builtin_amdgcn_mfma_f32_16x16x32_bf16(A3, b, zro, 0, 0, 0);       \
    PKV = _npk; }

#define CSTEP_ODD(S, PKV, AM) {                                               \
    int _nk = KS + (S) + 4; if (_nk > NITm1) _nk = NITm1;                     \
    int4v _npk = *(const int4v*)(pbase + (size_t)_nk * 64);                   \
    const char* _ab = abase + (S) * 4096;                                     \
    bf16x8 A0 = *(const bf16x8*)(_ab);                                        \
    bf16x8 A1 = *(const bf16x8*)(_ab + 1024);                                 \
    bf16x8 A2 = *(const bf16x8*)(_ab + 2048);                                 \
    bf16x8 A3 = *(const bf16x8*)(_ab + 3072);                                 \
    bf16x8 b = deq(lut, PKV);                                                 \
    sb0 = __builtin_amdgcn_mfma_f32_16x16x32_bf16(A0, b, sb0, 0, 0, 0);       \
    sb1 = __builtin_amdgcn_mfma_f32_16x16x32_bf16(A1, b, sb1, 0, 0, 0);       \
    sb2 = __builtin_amdgcn_mfma_f32_16x16x32_bf16(A2, b, sb2, 0, 0, 0);       \
    sb3 = __builtin_amdgcn_mfma_f32_16x16x32_bf16(A3, b, sb3, 0, 0, 0);       \
    mn0 += sb0 * (AM); mn1 += sb1 * (AM);                                     \
    mn2 += sb2 * (AM); mn3 += sb3 * (AM);                                     \
    PKV = _npk; }

// Fused NF4 dequant + GEMM. Block-shared LDS A-staging (double-buffered,
// 4 k-steps per phase), counted vmcnt(4) across ONE barrier per phase (pk
// HBM loads never drained), named-register pk ring (no arrays -> no scratch).
template<int NC>
__global__ __launch_bounds__(256, 4) void qlin_main(
    const int*   __restrict__ packed,
    const float* __restrict__ absmax,
    const unsigned short* __restrict__ xf,
    float*       __restrict__ parts) {
  constexpr int KCn   = IN_K / NC;     // k per chunk
  constexpr int NIT   = KCn / 32;      // k-steps per chunk (32 for NC=8)
  constexpr int NITm1 = NIT - 1;
  constexpr int NPH   = NIT / 4;       // phases (8)
  constexpr int AMX   = NIT / 2 - 1;   // last absmax group index in chunk
  constexpr int LOG   = (NC == 8) ? 3 : 2;

  __shared__ unsigned int lut[256];    // byte -> {bf16(nf4[lo]), bf16(nf4[hi])}
  __shared__ char astage[2 * 16384];   // double-buffered 4-k-step A tiles
  {
    int t = threadIdx.x;
    unsigned lo = f2bf(NF4_TAB[t & 15]);
    unsigned hi = f2bf(NF4_TAB[(t >> 4) & 15]);
    lut[t] = lo | (hi << 16);
  }
  __syncthreads();

  const int l     = threadIdx.x & 63;
  const int w     = threadIdx.x >> 6;
  const int ntile = (int)blockIdx.x >> LOG;
  const int chunk = (int)blockIdx.x & (NC - 1);
  const int col   = ntile * 64 + w * 16 + (l & 15);
  const int kb    = l >> 4;
  const int kc0   = chunk * KCn;
  const int ksg0  = kc0 >> 5;

  const char* pbase = (const char*)packed
                    + ((size_t)col * (IN_K / 2) + kc0 / 2) * 4 + kb * 16;
  const char* xfb = (const char*)xf + (size_t)ksg0 * 4096;   // chunk xf base
  const float* aptr = absmax + (size_t)col * 128 + (kc0 >> 6);

  const f32x4 zro = {0.f, 0.f, 0.f, 0.f};
  f32x4 mn0 = zro, mn1 = zro, mn2 = zro, mn3 = zro;
  f32x4 sb0, sb1, sb2, sb3;
  int4v pk0, pk1, pk2, pk3;

  // ---- prologue: absmax(2) -> stage phase0(4) -> pk ring(4); vmcnt(4)
  // retires absmax+stages (in-order), keeps the 4 pk loads in flight.
  float amE = aptr[0], amO = aptr[1];
  STAGE(0, 0);
  __builtin_amdgcn_sched_barrier(0);
  pk0 = *(const int4v*)(pbase);
  pk1 = *(const int4v*)(pbase + 64);
  pk2 = *(const int4v*)(pbase + 128);
  pk3 = *(const int4v*)(pbase + 192);
  asm volatile("s_waitcnt vmcnt(4)" ::: "memory");
  __builtin_amdgcn_s_barrier();

  for (int ph = 0; ph < NPH; ++ph) {
    const int KS  = ph * 4;
    const int cur = ph & 1;
    const char* abase = astage + cur * 16384 + l * 16;

    // next phase's absmax pair (oldest VMEM of this phase)
    int ia = 2 * ph + 2; if (ia > AMX) ia = AMX;
    int ib = 2 * ph + 3; if (ib > AMX) ib = AMX;
    float pmE = aptr[ia], pmO = aptr[ib];
    // stage next phase's A tile into the other buffer
    if (ph + 1 < NPH) STAGE(cur ^ 1, ph + 1);
    __builtin_amdgcn_sched_barrier(0);

    // 4 compute steps; each also issues one pk load (4 ahead)
    CSTEP_EVEN(0, pk0)
    CSTEP_ODD (1, pk1, amE)
    CSTEP_EVEN(2, pk2)
    CSTEP_ODD (3, pk3, amO)

    amE = pmE; amO = pmO;
    // counted wait: absmax + stages retired, <=4 pk still in flight;
    // lgkmcnt(0): this wave's LDS reads of buf `cur` done before others
    // may overwrite it (they only do so after this barrier).
    asm volatile("s_waitcnt vmcnt(4)" ::: "memory");
    asm volatile("s_waitcnt lgkmcnt(0)" ::: "memory");
    __builtin_amdgcn_s_barrier();
  }

  // epilogue: D mapping col=lane&15, row=(lane>>4)*4+reg; fp32 dword stores
  float* po = parts + (size_t)chunk * M_ROWS * OUT_N + col;
  const int rbase = kb * 4;
  po[(size_t)(0  + rbase + 0) * OUT_N] = mn0[0];
  po[(size_t)(0  + rbase + 1) * OUT_N] = mn0[1];
  po[(size_t)(0  + rbase + 2) * OUT_N] = mn0[2];
  po[(size_t)(0  + rbase + 3) * OUT_N] = mn0[3];
  po[(size_t)(16 + rbase + 0) * OUT_N] = mn1[0];
  po[(size_t)(16 + rbase + 1) * OUT_N] = mn1[1];
  po[(size_t)(16 + rbase + 2) * OUT_N] = mn1[2];
  po[(size_t)(16 + rbase + 3) * OUT_N] = mn1[3];
  po[(size_t)(32 + rbase + 0) * OUT_N] = mn2[0];
  po[(size_t)(32 + rbase + 1) * OUT_N] = mn2[1];
  po[(size_t)(32 + rbase + 2) * OUT_N] = mn2[2];
  po[(size_t)(32 + rbase + 3) * OUT_N] = mn2[3];
  po[(size_t)(48 + rbase + 0) * OUT_N] = mn3[0];
  po[(size_t)(48 + rbase + 1) * OUT_N] = mn3[1];
  po[(size_t)(48 + rbase + 2) * OUT_N] = mn3[2];
  po[(size_t)(48 + rbase + 3) * OUT_N] = mn3[3];
}

template<int NC>
__global__ __launch_bounds__(256) void qlin_reduce(
    const float* __restrict__ parts,
    const float* __restrict__ bias,
    float*       __restrict__ out) {
  const int TOT4 = M_ROWS * OUT_N / 4;   // 131072
  int i4 = blockIdx.x * 256 + threadIdx.x;
  if (i4 >= TOT4) return;
  const f32x4* p = (const f32x4*)parts;
  f32x4 s = p[i4];
  #pragma unroll
  for (int c = 1; c < NC; ++c) s += p[i4 + c * TOT4];
  f32x4 bb = ((const f32x4*)bias)[i4 & (OUT_N / 4 - 1)];
  ((f32x4*)out)[i4] = s + bb;
}

extern "C" void kernel_launch(void* const* d_in, const int* in_sizes, int n_in,
                              void* d_out, int out_size, void* d_ws, size_t ws_size,
                              hipStream_t stream) {
  const float* x      = (const float*)d_in[0];
  const int*   packed = (const int*)d_in[1];
  const float* absmax = (const float*)d_in[2];
  const float* bias   = (const float*)d_in[3];
  float* out = (float*)d_out;

  unsigned short* xf = (unsigned short*)d_ws;                  // 1 MB
  float* parts = (float*)((char*)d_ws + (1 << 20));            // NC * 2 MB fp32

  qlin_prep<<<(M_ROWS * IN_K / 8 + 255) / 256, 256, 0, stream>>>(x, xf);

  const size_t need8 = (size_t)(1 << 20)
                     + (size_t)8 * M_ROWS * OUT_N * sizeof(float);
  if (ws_size >= need8) {
    qlin_main<8><<<(OUT_N / 64) * 8, 256, 0, stream>>>(packed, absmax, xf, parts);
    qlin_reduce<8><<<(M_ROWS * OUT_N / 4 + 255) / 256, 256, 0, stream>>>(parts, bias, out);
  } else {
    qlin_main<4><<<(OUT_N / 64) * 4, 256, 0, stream>>>(packed, absmax, xf, parts);
    qlin_reduce<4><<<(M_ROWS * OUT_N / 4 + 255) / 256, 256, 0, stream>>>(parts, bias, out);
  }
}

// Round 8
// 40.985 us; speedup vs baseline: 2.4014x; 2.4014x over previous
//
#include <hip/hip_runtime.h>
#include <hip/hip_bf16.h>

#define OUT_N 8192
#define IN_K  8192
#define M_ROWS 64

typedef __attribute__((ext_vector_type(8))) short  bf16x8;
typedef __attribute__((ext_vector_type(4))) float  f32x4;
typedef __attribute__((ext_vector_type(4))) int    int4v;

__device__ const float NF4_TAB[16] = {
  -1.0f, -0.6961928009986877f, -0.5250730514526367f, -0.39491748809814453f,
  -0.28444138169288635f, -0.18477343022823334f, -0.09105003625154495f, 0.0f,
  0.07958029955625534f, 0.16093020141124725f, 0.24611230850219726f,
  0.33791524171829224f, 0.44070982933044434f, 0.5626170039176941f,
  0.7229568362236023f, 1.0f };

static __device__ __forceinline__ unsigned short f2bf(float f) {
  union { __hip_bfloat16 h; unsigned short s; } u;
  u.h = __float2bfloat16(f);
  return u.s;
}

static __device__ __forceinline__ void gload_lds16(const void* g, void* s) {
  __builtin_amdgcn_global_load_lds((const __attribute__((address_space(1))) void*)g,
                                   (__attribute__((address_space(3))) void*)s,
                                   16, 0, 0);
}

// Repack x (fp32 [64][8192]) -> bf16 MFMA A-fragment order.
// xf[((ks*4 + mt)*64 + lane)*8 + j] = bf16(x[mt*16+(lane&15)][ks*32+(lane>>4)*8+j])
__global__ __launch_bounds__(256) void qlin_prep(const float* __restrict__ x,
                                                 unsigned short* __restrict__ xf) {
  int t = blockIdx.x * 256 + threadIdx.x;          // (ks, mt, lane)
  int lane = t & 63, mt = (t >> 6) & 3, ks = t >> 8;
  int ri = lane & 15, kbb = lane >> 4;
  const float* src = x + (size_t)(mt * 16 + ri) * IN_K + ks * 32 + kbb * 8;
  f32x4 a = *(const f32x4*)src;
  f32x4 c = *(const f32x4*)(src + 4);
  bf16x8 o;
  o[0] = (short)f2bf(a[0]); o[1] = (short)f2bf(a[1]);
  o[2] = (short)f2bf(a[2]); o[3] = (short)f2bf(a[3]);
  o[4] = (short)f2bf(c[0]); o[5] = (short)f2bf(c[1]);
  o[6] = (short)f2bf(c[2]); o[7] = (short)f2bf(c[3]);
  ((bf16x8*)xf)[t] = o;
}

static __device__ __forceinline__ bf16x8 deq(const unsigned int* lut, int4v cur) {
  int4v bw;
  bw[0] = (int)lut[cur[0] & 255];
  bw[1] = (int)lut[cur[1] & 255];
  bw[2] = (int)lut[cur[2] & 255];
  bw[3] = (int)lut[cur[3] & 255];
  union { int4v i; bf16x8 h; } c; c.i = bw;
  return c.h;
}

// wave w stages k-step (4*PH + w) of the chunk into typed LDS buffer BUF, slot w.
#define STAGE(BUF, PH) {                                                      \
    const char* _s = xfb + (((size_t)(PH) * 4 + w) * 4096) + l * 16;          \
    gload_lds16(_s,        &ast[BUF][w][0]);                                  \
    gload_lds16(_s + 1024, &ast[BUF][w][64]);                                 \
    gload_lds16(_s + 2048, &ast[BUF][w][128]);                                \
    gload_lds16(_s + 3072, &ast[BUF][w][192]); }

// one k-step: typed ds_read A-frags, bpermute-redistribute pk, dequant, 4 MFMA,
// refill pk slot (+4 ahead, coalesced). EVEN opens 64k group, ODD closes (amax).
#define CSTEP_BODY(S, PKV)                                                    \
    int _nk = KS + (S) + 4; if (_nk > NITm1) _nk = NITm1;                     \
    int4v _npk = *(const int4v*)(pcoal + (size_t)_nk * 64);                   \
    bf16x8 A0 = ast[cur][S][l];                                               \
    bf16x8 A1 = ast[cur][S][64 + l];                                          \
    bf16x8 A2 = ast[cur][S][128 + l];                                         \
    bf16x8 A3 = ast[cur][S][192 + l];                                         \
    int4v _c;                                                                 \
    _c[0] = __builtin_amdgcn_ds_bpermute(bpidx, PKV[0]);                      \
    _c[1] = __builtin_amdgcn_ds_bpermute(bpidx, PKV[1]);                      \
    _c[2] = __builtin_amdgcn_ds_bpermute(bpidx, PKV[2]);                      \
    _c[3] = __builtin_amdgcn_ds_bpermute(bpidx, PKV[3]);                      \
    bf16x8 b = deq(lut, _c);

#define CSTEP_EVEN(S, PKV) {                                                  \
    CSTEP_BODY(S, PKV)                                                        \
    sb0 = __builtin_amdgcn_mfma_f32_16x16x32_bf16(A0, b, zro, 0, 0, 0);       \
    sb1 = __builtin_amdgcn_mfma_f32_16x16x32_bf16(A1, b, zro, 0, 0, 0);       \
    sb2 = __builtin_amdgcn_mfma_f32_16x16x32_bf16(A2, b, zro, 0, 0, 0);       \
    sb3 = __builtin_amdgcn_mfma_f32_16x16x32_bf16(A3, b, zro, 0, 0, 0);       \
    PKV = _npk; }

#define CSTEP_ODD(S, PKV, AM) {                                               \
    CSTEP_BODY(S, PKV)                                                        \
    sb0 = __builtin_amdgcn_mfma_f32_16x16x32_bf16(A0, b, sb0, 0, 0, 0);       \
    sb1 = __builtin_amdgcn_mfma_f32_16x16x32_bf16(A1, b, sb1, 0, 0, 0);       \
    sb2 = __builtin_amdgcn_mfma_f32_16x16x32_bf16(A2, b, sb2, 0, 0, 0);       \
    sb3 = __builtin_amdgcn_mfma_f32_16x16x32_bf16(A3, b, sb3, 0, 0, 0);       \
    mn0 += sb0 * (AM); mn1 += sb1 * (AM);                                     \
    mn2 += sb2 * (AM); mn3 += sb3 * (AM);                                     \
    PKV = _npk; }

// Fused NF4 dequant + GEMM.
// pk: coalesced 16-sector loads + ds_bpermute redistribution, 4-deep named ring.
// A: typed-LDS double-buffered staging (4 k-steps/phase), counted vmcnt(4) so
// pk HBM loads stay in flight across the one barrier per phase.
template<int NC>
__global__ __launch_bounds__(256, 4) void qlin_main(
    const int*   __restrict__ packed,
    const float* __restrict__ absmax,
    const unsigned short* __restrict__ xf,
    float*       __restrict__ parts) {
  constexpr int KCn   = IN_K / NC;     // k per chunk
  constexpr int NIT   = KCn / 32;      // k-steps per chunk (32 for NC=8)
  constexpr int NITm1 = NIT - 1;
  constexpr int NPH   = NIT / 4;       // phases
  constexpr int AMX   = NIT / 2 - 1;   // last absmax group in chunk
  constexpr int LOG   = (NC == 8) ? 3 : 2;

  __shared__ unsigned int lut[256];    // byte -> {bf16(nf4[lo]), bf16(nf4[hi])}
  __shared__ bf16x8 ast[2][4][256];    // typed: [buf][kstep-in-phase][mt*64+lane]
  {
    int t = threadIdx.x;
    unsigned lo = f2bf(NF4_TAB[t & 15]);
    unsigned hi = f2bf(NF4_TAB[(t >> 4) & 15]);
    lut[t] = lo | (hi << 16);
  }
  __syncthreads();

  const int l     = threadIdx.x & 63;
  const int w     = threadIdx.x >> 6;
  const int ntile = (int)blockIdx.x >> LOG;
  const int chunk = (int)blockIdx.x & (NC - 1);   // ~XCD id -> xf L2 locality
  const int colg0 = ntile * 64 + w * 16;
  const int col   = colg0 + (l & 15);
  const int kb    = l >> 4;
  const int kc0   = chunk * KCn;
  const int ksg0  = kc0 >> 5;

  // coalesced pk: lane l reads 16B piece (l&3) of col colg0+(l>>2); kstep stride 64B
  const char* pcoal = (const char*)packed
                    + ((size_t)(colg0 + (l >> 2)) * (IN_K / 2) + kc0 / 2) * 4
                    + (l & 3) * 16;
  // dest lane (c=l&15, q=l>>4) pulls from src lane 4c+q (byte index for bpermute)
  const int bpidx = (((l & 15) << 2) | (l >> 4)) << 2;

  const char* xfb = (const char*)xf + (size_t)ksg0 * 4096;   // chunk xf base
  const float* aptr = absmax + (size_t)col * 128 + (kc0 >> 6);

  const f32x4 zro = {0.f, 0.f, 0.f, 0.f};
  f32x4 mn0 = zro, mn1 = zro, mn2 = zro, mn3 = zro;
  f32x4 sb0, sb1, sb2, sb3;
  int4v pk0, pk1, pk2, pk3;

  // ---- prologue: absmax(2) -> stage phase0(4) -> [pin] -> pk ring(4)
  float amE = aptr[0], amO = aptr[1];
  STAGE(0, 0);
  __builtin_amdgcn_sched_barrier(0);
  pk0 = *(const int4v*)(pcoal);
  pk1 = *(const int4v*)(pcoal + 64);
  pk2 = *(const int4v*)(pcoal + 128);
  pk3 = *(const int4v*)(pcoal + 192);
  asm volatile("s_waitcnt vmcnt(4)" ::: "memory");   // stages+absmax retired
  __builtin_amdgcn_s_barrier();

  for (int ph = 0; ph < NPH; ++ph) {
    const int KS  = ph * 4;
    const int cur = ph & 1;

    int ia = 2 * ph + 2; if (ia > AMX) ia = AMX;
    int ib = 2 * ph + 3; if (ib > AMX) ib = AMX;
    float pmE = aptr[ia], pmO = aptr[ib];
    if (ph + 1 < NPH) STAGE(cur ^ 1, ph + 1);
    __builtin_amdgcn_sched_barrier(0);   // pin {absmax,stage} before {pk}

    CSTEP_EVEN(0, pk0)
    CSTEP_ODD (1, pk1, amE)
    CSTEP_EVEN(2, pk2)
    CSTEP_ODD (3, pk3, amO)

    amE = pmE; amO = pmO;
    // vmcnt(4): the 4 pk loads (youngest) may stay in flight; absmax+stages
    // (older, pinned) are provably retired -> buf^1 is ready for next phase.
    asm volatile("s_waitcnt vmcnt(4)" ::: "memory");
    asm volatile("s_waitcnt lgkmcnt(0)" ::: "memory"); // my reads of buf done
    __builtin_amdgcn_s_barrier();
  }

  // epilogue: D mapping col=lane&15, row=(lane>>4)*4+reg; fp32 dword stores
  float* po = parts + (size_t)chunk * M_ROWS * OUT_N + col;
  const int rbase = kb * 4;
  po[(size_t)(0  + rbase + 0) * OUT_N] = mn0[0];
  po[(size_t)(0  + rbase + 1) * OUT_N] = mn0[1];
  po[(size_t)(0  + rbase + 2) * OUT_N] = mn0[2];
  po[(size_t)(0  + rbase + 3) * OUT_N] = mn0[3];
  po[(size_t)(16 + rbase + 0) * OUT_N] = mn1[0];
  po[(size_t)(16 + rbase + 1) * OUT_N] = mn1[1];
  po[(size_t)(16 + rbase + 2) * OUT_N] = mn1[2];
  po[(size_t)(16 + rbase + 3) * OUT_N] = mn1[3];
  po[(size_t)(32 + rbase + 0) * OUT_N] = mn2[0];
  po[(size_t)(32 + rbase + 1) * OUT_N] = mn2[1];
  po[(size_t)(32 + rbase + 2) * OUT_N] = mn2[2];
  po[(size_t)(32 + rbase + 3) * OUT_N] = mn2[3];
  po[(size_t)(48 + rbase + 0) * OUT_N] = mn3[0];
  po[(size_t)(48 + rbase + 1) * OUT_N] = mn3[1];
  po[(size_t)(48 + rbase + 2) * OUT_N] = mn3[2];
  po[(size_t)(48 + rbase + 3) * OUT_N] = mn3[3];
}

template<int NC>
__global__ __launch_bounds__(256) void qlin_reduce(
    const float* __restrict__ parts,
    const float* __restrict__ bias,
    float*       __restrict__ out) {
  const int TOT4 = M_ROWS * OUT_N / 4;   // 131072
  int i4 = blockIdx.x * 256 + threadIdx.x;
  if (i4 >= TOT4) return;
  const f32x4* p = (const f32x4*)parts;
  f32x4 s = p[i4];
  #pragma unroll
  for (int c = 1; c < NC; ++c) s += p[i4 + c * TOT4];
  f32x4 bb = ((const f32x4*)bias)[i4 & (OUT_N / 4 - 1)];
  ((f32x4*)out)[i4] = s + bb;
}

extern "C" void kernel_launch(void* const* d_in, const int* in_sizes, int n_in,
                              void* d_out, int out_size, void* d_ws, size_t ws_size,
                              hipStream_t stream) {
  const float* x      = (const float*)d_in[0];
  const int*   packed = (const int*)d_in[1];
  const float* absmax = (const float*)d_in[2];
  const float* bias   = (const float*)d_in[3];
  float* out = (float*)d_out;

  unsigned short* xf = (unsigned short*)d_ws;                  // 1 MB
  float* parts = (float*)((char*)d_ws + (1 << 20));            // NC * 2 MB fp32

  qlin_prep<<<(M_ROWS * IN_K / 8 + 255) / 256, 256, 0, stream>>>(x, xf);

  const size_t need8 = (size_t)(1 << 20)
                     + (size_t)8 * M_ROWS * OUT_N * sizeof(float);
  if (ws_size >= need8) {
    qlin_main<8><<<(OUT_N / 64) * 8, 256, 0, stream>>>(packed, absmax, xf, parts);
    qlin_reduce<8><<<(M_ROWS * OUT_N / 4 + 255) / 256, 256, 0, stream>>>(parts, bias, out);
  } else {
    qlin_main<4><<<(OUT_N / 64) * 4, 256, 0, stream>>>(packed, absmax, xf, parts);
    qlin_reduce<4><<<(M_ROWS * OUT_N / 4 + 255) / 256, 256, 0, stream>>>(parts, bias, out);
  }
}